// Round 4
// baseline (142.447 us; speedup 1.0000x reference)
//
#include <hip/hip_runtime.h>
#include <math.h>

#define BH 256
#define BW 256
#define NB 32
#define NC 32
#define RB 64   // reduction blocks per batch

typedef float nfloat4 __attribute__((ext_vector_type(4)));  // native vec for nontemporal builtin

// ---------------- Kernel 1: per-batch weighted sum  S[b] = sum x[b,h,w,c]*Wm[c]
__global__ __launch_bounds__(256) void k_reduce(const float* __restrict__ x,
                                                const float* __restrict__ Wm,
                                                float* __restrict__ partial) {
    const int b   = blockIdx.y;
    const int blk = blockIdx.x;
    const int tid = blk * 256 + threadIdx.x;            // 0..16383 within batch
    const int threads_per_batch = RB * 256;             // 16384
    // stride in elements = 16384*4 = 65536, divisible by NC=32 ->
    // channel base is loop-invariant per thread.
    const int cb = (tid * 4) & (NC - 1);
    const float w0 = Wm[cb + 0], w1 = Wm[cb + 1], w2 = Wm[cb + 2], w3 = Wm[cb + 3];

    const float4* xb = (const float4*)(x + (size_t)b * BH * BW * NC);
    const int n4 = BH * BW * NC / 4;                    // 524288
    float s0 = 0.f, s1 = 0.f;
    for (int i = tid; i < n4; i += 2 * threads_per_batch) {
        float4 v0 = xb[i];
        float4 v1 = xb[i + threads_per_batch];
        s0 += v0.x * w0 + v0.y * w1 + v0.z * w2 + v0.w * w3;
        s1 += v1.x * w0 + v1.y * w1 + v1.z * w2 + v1.w * w3;
    }
    float s = s0 + s1;
    for (int off = 32; off; off >>= 1) s += __shfl_down(s, off, 64);
    __shared__ float red[4];
    const int lane = threadIdx.x & 63, wv = threadIdx.x >> 6;
    if (lane == 0) red[wv] = s;
    __syncthreads();
    if (threadIdx.x == 0)
        partial[b * RB + blk] = red[0] + red[1] + red[2] + red[3];
}

// ---------------- Kernel 2: bilinear rotate, 2-D tiled.
// Block = 256 threads = 32 pixel-slots (8 wide x 4 tall) x 8 channel-groups.
// Intra-block tap reuse: the 4 bilinear taps of all 32 pixels touch ~45 unique
// 128B lines (5.8 KB) -> L1-resident, instead of re-fetching from L3 per tap.
// Each block re-derives its batch's angle from the 64 partials (wave 0,
// shuffle-reduced) -> no separate angle kernel, deterministic.
// Output stores NONTEMPORAL so 256 MB of writes don't evict x from L3.
__global__ __launch_bounds__(256) void k_rotate(const float* __restrict__ x,
                                                const float* __restrict__ partial,
                                                const float* __restrict__ bias,
                                                float* __restrict__ out) {
    const int blk    = blockIdx.x;
    const int b      = blk >> 11;        // / 2048 tiles per image
    const int rem    = blk & 2047;
    const int tile_x = rem & 31;         // 32 tiles across (8 px each)
    const int tile_y = rem >> 5;         // 64 tiles down (4 rows each)

    __shared__ float4 sprm;
    if (threadIdx.x < 64) {
        float s = partial[b * RB + (threadIdx.x & 63)];
        for (int off = 32; off; off >>= 1) s += __shfl_down(s, off, 64);
        if (threadIdx.x == 0) {
            const float pi = 3.14159265358979323846f;
            float angle = tanhf(s * (1.f / (BH * BW)) + bias[0]) * pi;
            angle = fminf(fmaxf(angle, -pi), pi);
            const float cc = cosf(angle), sn = sinf(angle);
            const float w1 = (float)(BW - 1), h1 = (float)(BH - 1);
            const float xoff = (w1 - (cc * w1 - sn * h1)) * 0.5f;
            const float yoff = (h1 - (sn * w1 + cc * h1)) * 0.5f;
            sprm = make_float4(cc, sn, xoff, yoff);
        }
    }
    __syncthreads();
    const float4 prm = sprm;

    const int c4 = (threadIdx.x & 7) * 4;        // channel base
    const int px = threadIdx.x >> 3;             // 0..31 pixel slot
    const int xo = tile_x * 8 + (px & 7);
    const int yo = tile_y * 4 + (px >> 3);

    const float cc = prm.x, sn = prm.y, xoff = prm.z, yoff = prm.w;
    const float fx = (float)xo, fy = (float)yo;
    const float in_x = cc * fx - sn * fy + xoff;
    const float in_y = sn * fx + cc * fy + yoff;
    const float x0 = floorf(in_x), y0 = floorf(in_y);
    const float wx = in_x - x0, wy = in_y - y0;
    const int x0i = (int)x0, y0i = (int)y0;

    const float* xb = x + (size_t)b * (BH * BW * NC);

    auto pix = [&](int yi, int xi) -> float4 {
        const bool valid = (xi >= 0) & (xi < BW) & (yi >= 0) & (yi < BH);
        const int yc = min(max(yi, 0), BH - 1);
        const int xc = min(max(xi, 0), BW - 1);
        float4 v = *(const float4*)(xb + ((size_t)yc * BW + xc) * NC + c4);
        const float f = valid ? 1.f : 0.f;
        v.x *= f; v.y *= f; v.z *= f; v.w *= f;
        return v;
    };

    const float4 v00 = pix(y0i, x0i);
    const float4 v01 = pix(y0i, x0i + 1);
    const float4 v10 = pix(y0i + 1, x0i);
    const float4 v11 = pix(y0i + 1, x0i + 1);

    const float owx = 1.f - wx, owy = 1.f - wy;
    nfloat4 r;
    r.x = (v00.x * owx + v01.x * wx) * owy + (v10.x * owx + v11.x * wx) * wy;
    r.y = (v00.y * owx + v01.y * wx) * owy + (v10.y * owx + v11.y * wx) * wy;
    r.z = (v00.z * owx + v01.z * wx) * owy + (v10.z * owx + v11.z * wx) * wy;
    r.w = (v00.w * owx + v01.w * wx) * owy + (v10.w * owx + v11.w * wx) * wy;

    float* op = out + (((size_t)b * BH * BW + (size_t)yo * BW + xo) * NC + c4);
    __builtin_nontemporal_store(r, (nfloat4*)op);
}

extern "C" void kernel_launch(void* const* d_in, const int* in_sizes, int n_in,
                              void* d_out, int out_size, void* d_ws, size_t ws_size,
                              hipStream_t stream) {
    const float* x    = (const float*)d_in[0];
    const float* Wm   = (const float*)d_in[1];
    const float* bias = (const float*)d_in[2];
    float* out = (float*)d_out;

    float* partial = (float*)d_ws;                      // NB*RB floats = 8 KiB

    dim3 g1(RB, NB);
    k_reduce<<<g1, 256, 0, stream>>>(x, Wm, partial);

    const int nblocks = NB * 2048;                      // 65536 tiles
    k_rotate<<<nblocks, 256, 0, stream>>>(x, partial, bias, out);
}

// Round 5
// 132.474 us; speedup vs baseline: 1.0753x; 1.0753x over previous
//
#include <hip/hip_runtime.h>
#include <math.h>

#define BH 256
#define BW 256
#define NB 32
#define NC 32
#define RB 64   // reduction blocks per batch

typedef float nfloat4 __attribute__((ext_vector_type(4)));  // native vec for nontemporal builtin

// ---------------- Kernel 1: per-batch weighted sum  S[b] = sum x[b,h,w,c]*Wm[c]
__global__ __launch_bounds__(256) void k_reduce(const float* __restrict__ x,
                                                const float* __restrict__ Wm,
                                                float* __restrict__ partial) {
    const int b   = blockIdx.y;
    const int blk = blockIdx.x;
    const int tid = blk * 256 + threadIdx.x;            // 0..16383 within batch
    const int threads_per_batch = RB * 256;             // 16384
    const int cb = (tid * 4) & (NC - 1);
    const float w0 = Wm[cb + 0], w1 = Wm[cb + 1], w2 = Wm[cb + 2], w3 = Wm[cb + 3];

    const float4* xb = (const float4*)(x + (size_t)b * BH * BW * NC);
    const int n4 = BH * BW * NC / 4;                    // 524288
    float s0 = 0.f, s1 = 0.f;
    for (int i = tid; i < n4; i += 2 * threads_per_batch) {
        float4 v0 = xb[i];
        float4 v1 = xb[i + threads_per_batch];
        s0 += v0.x * w0 + v0.y * w1 + v0.z * w2 + v0.w * w3;
        s1 += v1.x * w0 + v1.y * w1 + v1.z * w2 + v1.w * w3;
    }
    float s = s0 + s1;
    for (int off = 32; off; off >>= 1) s += __shfl_down(s, off, 64);
    __shared__ float red[4];
    const int lane = threadIdx.x & 63, wv = threadIdx.x >> 6;
    if (lane == 0) red[wv] = s;
    __syncthreads();
    if (threadIdx.x == 0)
        partial[b * RB + blk] = red[0] + red[1] + red[2] + red[3];
}

// ---------------- Kernel 2: finish reduction, compute per-batch rotation params
__global__ void k_angle(const float* __restrict__ partial,
                        const float* __restrict__ bias,
                        float4* __restrict__ params) {
    const int b = threadIdx.x;
    if (b >= NB) return;
    float s = 0.f;
    for (int i = 0; i < RB; ++i) s += partial[b * RB + i];
    const float pi = 3.14159265358979323846f;
    float angle = tanhf(s * (1.f / (BH * BW)) + bias[0]) * pi;
    angle = fminf(fmaxf(angle, -pi), pi);
    const float cc = cosf(angle), ss = sinf(angle);
    const float w1 = (float)(BW - 1), h1 = (float)(BH - 1);
    const float xoff = (w1 - (cc * w1 - ss * h1)) * 0.5f;
    const float yoff = (h1 - (ss * w1 + cc * h1)) * 0.5f;
    params[b] = make_float4(cc, ss, xoff, yoff);
}

// ---------------- Kernel 3: bilinear rotate, 2-D tiled.
// Block = 256 threads = 32 pixel-slots (8 wide x 4 tall) x 8 channel-groups.
// Intra-block tap reuse: taps of all 32 pixels touch ~45 unique 128B lines
// (5.8 KB) -> L1-resident. Params read as broadcast float4 (no prologue/barrier
// -- R4's per-block angle re-derivation serialized short blocks and regressed).
// Output stores NONTEMPORAL so 256 MB of writes don't evict x from L3.
__global__ __launch_bounds__(256) void k_rotate(const float* __restrict__ x,
                                                const float4* __restrict__ params,
                                                float* __restrict__ out) {
    const int blk    = blockIdx.x;
    const int b      = blk >> 11;        // 2048 tiles per image
    const int rem    = blk & 2047;
    const int tile_x = rem & 31;         // 32 tiles across (8 px each)
    const int tile_y = rem >> 5;         // 64 tiles down (4 rows each)

    const float4 prm = params[b];

    const int c4 = (threadIdx.x & 7) * 4;        // channel base
    const int px = threadIdx.x >> 3;             // 0..31 pixel slot
    const int xo = tile_x * 8 + (px & 7);
    const int yo = tile_y * 4 + (px >> 3);

    const float cc = prm.x, sn = prm.y, xoff = prm.z, yoff = prm.w;
    const float fx = (float)xo, fy = (float)yo;
    const float in_x = cc * fx - sn * fy + xoff;
    const float in_y = sn * fx + cc * fy + yoff;
    const float x0 = floorf(in_x), y0 = floorf(in_y);
    const float wx = in_x - x0, wy = in_y - y0;
    const int x0i = (int)x0, y0i = (int)y0;

    const float* xb = x + (size_t)b * (BH * BW * NC);

    auto pix = [&](int yi, int xi) -> float4 {
        const bool valid = (xi >= 0) & (xi < BW) & (yi >= 0) & (yi < BH);
        const int yc = min(max(yi, 0), BH - 1);
        const int xc = min(max(xi, 0), BW - 1);
        float4 v = *(const float4*)(xb + ((size_t)yc * BW + xc) * NC + c4);
        const float f = valid ? 1.f : 0.f;
        v.x *= f; v.y *= f; v.z *= f; v.w *= f;
        return v;
    };

    const float4 v00 = pix(y0i, x0i);
    const float4 v01 = pix(y0i, x0i + 1);
    const float4 v10 = pix(y0i + 1, x0i);
    const float4 v11 = pix(y0i + 1, x0i + 1);

    const float owx = 1.f - wx, owy = 1.f - wy;
    nfloat4 r;
    r.x = (v00.x * owx + v01.x * wx) * owy + (v10.x * owx + v11.x * wx) * wy;
    r.y = (v00.y * owx + v01.y * wx) * owy + (v10.y * owx + v11.y * wx) * wy;
    r.z = (v00.z * owx + v01.z * wx) * owy + (v10.z * owx + v11.z * wx) * wy;
    r.w = (v00.w * owx + v01.w * wx) * owy + (v10.w * owx + v11.w * wx) * wy;

    float* op = out + (((size_t)b * BH * BW + (size_t)yo * BW + xo) * NC + c4);
    __builtin_nontemporal_store(r, (nfloat4*)op);
}

extern "C" void kernel_launch(void* const* d_in, const int* in_sizes, int n_in,
                              void* d_out, int out_size, void* d_ws, size_t ws_size,
                              hipStream_t stream) {
    const float* x    = (const float*)d_in[0];
    const float* Wm   = (const float*)d_in[1];
    const float* bias = (const float*)d_in[2];
    float* out = (float*)d_out;

    float*  partial = (float*)d_ws;                         // NB*RB floats = 8 KiB
    float4* params  = (float4*)((char*)d_ws + NB * RB * sizeof(float));

    dim3 g1(RB, NB);
    k_reduce<<<g1, 256, 0, stream>>>(x, Wm, partial);
    k_angle<<<1, 64, 0, stream>>>(partial, bias, params);

    const int nblocks = NB * 2048;                          // 65536 tiles
    k_rotate<<<nblocks, 256, 0, stream>>>(x, params, out);
}

// Round 7
// 130.501 us; speedup vs baseline: 1.0915x; 1.0151x over previous
//
#include <hip/hip_runtime.h>
#include <math.h>

#define BH 256
#define BW 256
#define NB 32
#define NC 32
#define RB 64   // reduction blocks per batch

typedef float nfloat4 __attribute__((ext_vector_type(4)));  // native vec for nontemporal builtin

// ---------------- Kernel 1: per-batch weighted sum  S[b] = sum x[b,h,w,c]*Wm[c]
// Per-thread loop walks DESCENDING addresses: at kernel end the MRU lines in
// L3 are each batch's HEAD, matching k_rotate's ascending read order (rotate
// then reads MRU-first while evictions consume the stale tails it needs last).
__global__ __launch_bounds__(256) void k_reduce(const float* __restrict__ x,
                                                const float* __restrict__ Wm,
                                                float* __restrict__ partial) {
    const int b   = blockIdx.y;
    const int blk = blockIdx.x;
    const int tid = blk * 256 + threadIdx.x;            // 0..16383 within batch
    const int tpb = RB * 256;                           // 16384
    const int cb = (tid * 4) & (NC - 1);
    const float w0 = Wm[cb + 0], w1 = Wm[cb + 1], w2 = Wm[cb + 2], w3 = Wm[cb + 3];

    const float4* xb = (const float4*)(x + (size_t)b * BH * BW * NC);
    const int n4 = BH * BW * NC / 4;                    // 524288
    float s0 = 0.f, s1 = 0.f;
    // descending 2-deep strided walk over the same index set as before
    for (int i = n4 - 2 * tpb + tid; i >= 0; i -= 2 * tpb) {
        float4 v0 = xb[i + tpb];
        float4 v1 = xb[i];
        s0 += v0.x * w0 + v0.y * w1 + v0.z * w2 + v0.w * w3;
        s1 += v1.x * w0 + v1.y * w1 + v1.z * w2 + v1.w * w3;
    }
    float s = s0 + s1;
    for (int off = 32; off; off >>= 1) s += __shfl_down(s, off, 64);
    __shared__ float red[4];
    const int lane = threadIdx.x & 63, wv = threadIdx.x >> 6;
    if (lane == 0) red[wv] = s;
    __syncthreads();
    if (threadIdx.x == 0)
        partial[b * RB + blk] = red[0] + red[1] + red[2] + red[3];
}

// ---------------- Kernel 2: finish reduction, compute per-batch rotation params
__global__ void k_angle(const float* __restrict__ partial,
                        const float* __restrict__ bias,
                        float4* __restrict__ params) {
    const int b = threadIdx.x;
    if (b >= NB) return;
    float s = 0.f;
    for (int i = 0; i < RB; ++i) s += partial[b * RB + i];
    const float pi = 3.14159265358979323846f;
    float angle = tanhf(s * (1.f / (BH * BW)) + bias[0]) * pi;
    angle = fminf(fmaxf(angle, -pi), pi);
    const float cc = cosf(angle), ss = sinf(angle);
    const float w1 = (float)(BW - 1), h1 = (float)(BH - 1);
    const float xoff = (w1 - (cc * w1 - ss * h1)) * 0.5f;
    const float yoff = (h1 - (ss * w1 + cc * h1)) * 0.5f;
    params[b] = make_float4(cc, ss, xoff, yoff);
}

// ---------------- Kernel 3: bilinear rotate, one thread per (pixel, 4 channels)
// Ascending order (matches reduce's end-state MRU = heads). NT stores so the
// 256 MB of output writes pollute L3 as little as possible.
__global__ __launch_bounds__(256) void k_rotate(const float* __restrict__ x,
                                                const float4* __restrict__ params,
                                                float* __restrict__ out) {
    const int gid = blockIdx.x * 256 + threadIdx.x;     // 0 .. 16,777,215
    const int c4  = (gid & 7) * 4;
    const int pid = gid >> 3;
    const int b   = pid >> 16;
    const int p   = pid & 65535;
    const int yo  = p >> 8;
    const int xo  = p & 255;

    const float4 prm = params[b];
    const float cc = prm.x, sn = prm.y, xoff = prm.z, yoff = prm.w;
    const float fx = (float)xo, fy = (float)yo;
    const float in_x = cc * fx - sn * fy + xoff;
    const float in_y = sn * fx + cc * fy + yoff;
    const float x0 = floorf(in_x), y0 = floorf(in_y);
    const float wx = in_x - x0, wy = in_y - y0;
    const int x0i = (int)x0, y0i = (int)y0;

    const float* xb = x + (size_t)b * (BH * BW * NC);

    auto pix = [&](int yi, int xi) -> float4 {
        const bool valid = (xi >= 0) & (xi < BW) & (yi >= 0) & (yi < BH);
        const int yc = min(max(yi, 0), BH - 1);
        const int xc = min(max(xi, 0), BW - 1);
        float4 v = *(const float4*)(xb + ((size_t)yc * BW + xc) * NC + c4);
        const float f = valid ? 1.f : 0.f;
        v.x *= f; v.y *= f; v.z *= f; v.w *= f;
        return v;
    };

    const float4 v00 = pix(y0i, x0i);
    const float4 v01 = pix(y0i, x0i + 1);
    const float4 v10 = pix(y0i + 1, x0i);
    const float4 v11 = pix(y0i + 1, x0i + 1);

    const float owx = 1.f - wx, owy = 1.f - wy;
    nfloat4 r;
    r.x = (v00.x * owx + v01.x * wx) * owy + (v10.x * owx + v11.x * wx) * wy;
    r.y = (v00.y * owx + v01.y * wx) * owy + (v10.y * owx + v11.y * wx) * wy;
    r.z = (v00.z * owx + v01.z * wx) * owy + (v10.z * owx + v11.z * wx) * wy;
    r.w = (v00.w * owx + v01.w * wx) * owy + (v10.w * owx + v11.w * wx) * wy;

    __builtin_nontemporal_store(r, (nfloat4*)(out + (size_t)gid * 4));
}

extern "C" void kernel_launch(void* const* d_in, const int* in_sizes, int n_in,
                              void* d_out, int out_size, void* d_ws, size_t ws_size,
                              hipStream_t stream) {
    const float* x    = (const float*)d_in[0];
    const float* Wm   = (const float*)d_in[1];
    const float* bias = (const float*)d_in[2];
    float* out = (float*)d_out;

    float*  partial = (float*)d_ws;                         // NB*RB floats = 8 KiB
    float4* params  = (float4*)((char*)d_ws + NB * RB * sizeof(float));

    dim3 g1(RB, NB);
    k_reduce<<<g1, 256, 0, stream>>>(x, Wm, partial);
    k_angle<<<1, 64, 0, stream>>>(partial, bias, params);

    const int total4 = NB * BH * BW * NC / 4;               // 16,777,216
    k_rotate<<<total4 / 256, 256, 0, stream>>>(x, params, out);
}